// Round 1
// 266.976 us; speedup vs baseline: 1.3859x; 1.3859x over previous
//
#include <hip/hip_runtime.h>
#include <math.h>

// Problem: B=4, S=4096, D=2048, E=64, TOP_K=2
#define M_TOK 16384
#define D_DIM 2048
#define E_EXP 64
#define NCOL  128              // route cols 0..63 | noise cols 64..127
#define BM    64               // tokens per block
#define BK    64               // K per main-loop iteration (2 MFMA substeps of 32)
#define NITER (D_DIM / BK)     // 32

typedef float  f32x4  __attribute__((ext_vector_type(4)));
typedef short  bf16x8 __attribute__((ext_vector_type(8)));

#define MFMA_B16(a, b, c) __builtin_amdgcn_mfma_f32_16x16x32_bf16((a), (b), (c), 0, 0, 0)

// f32 -> bf16 round-to-nearest-even (no NaN handling; inputs are finite randoms)
__device__ __forceinline__ unsigned short bfrne(float f) {
    unsigned int u = __float_as_uint(f);
    return (unsigned short)((u + 0x7fffu + ((u >> 16) & 1u)) >> 16);
}
__device__ __forceinline__ float bfhi(unsigned short h) {
    return __uint_as_float((unsigned int)h << 16);
}

// jax.lax.top_k order: larger value first; ties -> lower index first
__device__ __forceinline__ bool beats(double va, int ia, double vb, int ib) {
    return (va > vb) || (va == vb && ia < ib);
}

__device__ __forceinline__ void gload16(const void* g, void* lds) {
    __builtin_amdgcn_global_load_lds(
        (const __attribute__((address_space(1))) unsigned int*)g,
        (__attribute__((address_space(3))) unsigned int*)lds, 16, 0, 0);
}

// ---------------- prep: split W_route|W_noise into 3 bf16 limbs, frag-linear ----------
// Wg layout (16B units): [kblk 0..63][limb 0..2][cf 0..7][lane 0..63]
//   cf 0..3 -> route cols cf*16+(lane&15); cf 4..7 -> noise cols (cf-4)*16+(lane&15)
//   lane holds k = kblk*32 + (lane>>4)*8 + j  (exactly the mfma_16x16x32 B-frag order)
__global__ __launch_bounds__(256) void prep_w(
    const float* __restrict__ Wr, const float* __restrict__ Wn,
    unsigned short* __restrict__ Wg)
{
    const int g    = blockIdx.x * 256 + threadIdx.x;   // 0..32767
    const int lane = g & 63;
    const int cf   = (g >> 6) & 7;
    const int kblk = g >> 9;                           // 0..63
    const int colL = (cf & 3) * 16 + (lane & 15);
    const float* __restrict__ W = (cf < 4) ? Wr : Wn;
    const int kbase = kblk * 32 + (lane >> 4) * 8;

    bf16x8 o0, o1, o2;
    #pragma unroll
    for (int j = 0; j < 8; ++j) {
        const float w = W[(size_t)(kbase + j) * E_EXP + colL];
        const unsigned short h0 = bfrne(w);
        const float r  = w - bfhi(h0);              // exact (Sterbenz)
        const unsigned short h1 = bfrne(r);
        const float r2 = r - bfhi(h1);              // exact
        const unsigned short h2 = bfrne(r2);
        o0[j] = (short)h0; o1[j] = (short)h1; o2[j] = (short)h2;
    }
    const size_t s0 = (((size_t)kblk * 3 + 0) * 8 + cf) * 64 + lane;
    const size_t s1 = (((size_t)kblk * 3 + 1) * 8 + cf) * 64 + lane;
    const size_t s2 = (((size_t)kblk * 3 + 2) * 8 + cf) * 64 + lane;
    *(bf16x8*)(Wg + s0 * 8) = o0;
    *(bf16x8*)(Wg + s1 * 8) = o1;
    *(bf16x8*)(Wg + s2 * 8) = o2;
}

// ---------------- fused: 3-limb bf16 MFMA GEMM + softplus + top-2 + softmax ----------
__device__ __forceinline__ void load_b(const unsigned short* __restrict__ Wg,
                                       int it, int wc, int lane,
                                       bf16x8 (&Bv)[2][2][3])
{
    #pragma unroll
    for (int s = 0; s < 2; ++s) {
        const int kblk = it * 2 + s;
        #pragma unroll
        for (int cfi = 0; cfi < 2; ++cfi) {
            #pragma unroll
            for (int p = 0; p < 3; ++p) {
                const size_t idx = (((size_t)kblk * 3 + p) * 8 + (wc * 2 + cfi)) * 64 + lane;
                Bv[s][cfi][p] = *(const bf16x8*)(Wg + idx * 8);
            }
        }
    }
}

// A tile [64 tok][64 k] f32 in LDS, XOR-swizzled: phys_byte = log_byte ^ ((tok&7)<<4).
// global_load_lds writes linearly; we pre-swizzle the GLOBAL source per lane (rule 21).
__device__ __forceinline__ void stage_a(const float* __restrict__ A, float* Alds,
                                        int buf, int k0, int tokBase, int tid)
{
    #pragma unroll
    for (int i = 0; i < 2; ++i) {
        const int c    = i * 512 + tid;            // 16B chunk id, 0..1023
        const int tok  = c >> 4;                   // 16 chunks per 256B row
        const int off  = (c & 15) * 16;
        const int soff = off ^ ((tok & 7) << 4);
        const float* g = A + (size_t)(tokBase + tok) * D_DIM + k0 + (soff >> 2);
        char* l = (char*)Alds + buf * (BM * BK * 4) + i * 8192 + (tid >> 6) * 1024;
        gload16(g, l);   // HW dest = l + lane*16  == linear chunk c
    }
}

__device__ __forceinline__ void split8(const float4& a, const float4& b,
                                       bf16x8& o0, bf16x8& o1, bf16x8& o2)
{
    const float v[8] = {a.x, a.y, a.z, a.w, b.x, b.y, b.z, b.w};
    #pragma unroll
    for (int j = 0; j < 8; ++j) {
        const unsigned short h0 = bfrne(v[j]);
        const float r  = v[j] - bfhi(h0);
        const unsigned short h1 = bfrne(r);
        const float r2 = r - bfhi(h1);
        const unsigned short h2 = bfrne(r2);
        o0[j] = (short)h0; o1[j] = (short)h1; o2[j] = (short)h2;
    }
}

__device__ __forceinline__ void compute_iter(const float* Abuf, int wr, int wc, int lane,
                                             const bf16x8 (&Bc)[2][2][3],
                                             f32x4 (&acch)[2][2], f32x4 (&accl)[2][2])
{
    const char* Ab = (const char*)Abuf;
    #pragma unroll
    for (int s = 0; s < 2; ++s) {
        bf16x8 a0[2], a1[2], a2[2];
        #pragma unroll
        for (int rf = 0; rf < 2; ++rf) {
            const int row  = wr * 32 + rf * 16 + (lane & 15);
            const int base = row * 256 + s * 128 + (lane >> 4) * 32;
            const int sw   = (row & 7) << 4;
            const float4 p = *(const float4*)(Ab + (base ^ sw));
            const float4 q = *(const float4*)(Ab + ((base + 16) ^ sw));
            split8(p, q, a0[rf], a1[rf], a2[rf]);
        }
        #pragma unroll
        for (int cfi = 0; cfi < 2; ++cfi) {
            #pragma unroll
            for (int rf = 0; rf < 2; ++rf) {
                // hi limb product -> short dep chain in acch; 5 low products -> accl
                acch[rf][cfi] = MFMA_B16(a0[rf], Bc[s][cfi][0], acch[rf][cfi]);
                accl[rf][cfi] = MFMA_B16(a0[rf], Bc[s][cfi][1], accl[rf][cfi]);
                accl[rf][cfi] = MFMA_B16(a1[rf], Bc[s][cfi][0], accl[rf][cfi]);
                accl[rf][cfi] = MFMA_B16(a1[rf], Bc[s][cfi][1], accl[rf][cfi]);
                accl[rf][cfi] = MFMA_B16(a0[rf], Bc[s][cfi][2], accl[rf][cfi]);
                accl[rf][cfi] = MFMA_B16(a2[rf], Bc[s][cfi][0], accl[rf][cfi]);
            }
        }
    }
}

__global__ __launch_bounds__(512, 2) void fused_router(
    const float* __restrict__ A,
    const unsigned short* __restrict__ Wg,
    const float* __restrict__ br, const float* __restrict__ bn,
    const float* __restrict__ noise,
    float* __restrict__ probs, float* __restrict__ idxo)
{
    __shared__ float Alds[2 * BM * BK];       // 32 KB, double-buffered, swizzled
    __shared__ float Llds[BM][NCOL + 1];      // 64 x 129 f32 logits scratch

    const int tid  = threadIdx.x;
    const int lane = tid & 63;
    const int wid  = tid >> 6;       // 0..7
    const int wr   = wid >> 2;       // token half  (32 tokens)
    const int wc   = wid & 3;        // col quarter (32 of 128 cols)
    const int tokBase = blockIdx.x * BM;

    f32x4 acch[2][2], accl[2][2];
    const f32x4 zero4 = {0.f, 0.f, 0.f, 0.f};
    #pragma unroll
    for (int a = 0; a < 2; ++a)
        #pragma unroll
        for (int b = 0; b < 2; ++b) { acch[a][b] = zero4; accl[a][b] = zero4; }

    bf16x8 B0[2][2][3], B1[2][2][3];
    load_b(Wg, 0, wc, lane, B0);
    stage_a(A, Alds, 0, 0, tokBase, tid);
    asm volatile("s_waitcnt vmcnt(0)" ::: "memory");
    __syncthreads();

    #pragma unroll 1
    for (int it2 = 0; it2 < NITER / 2; ++it2) {
        const int ita = it2 * 2;
        const int itb = ita + 1;                 // always < NITER (NITER even)
        load_b(Wg, itb, wc, lane, B1);           // prefetch B (regs) + A (LDS) for itb
        stage_a(A, Alds, 1, itb * BK, tokBase, tid);
        compute_iter(Alds, wr, wc, lane, B0, acch, accl);
        asm volatile("s_waitcnt vmcnt(0)" ::: "memory");
        __syncthreads();
        if (itb + 1 < NITER) {
            load_b(Wg, itb + 1, wc, lane, B0);
            stage_a(A, Alds, 0, (itb + 1) * BK, tokBase, tid);
        }
        compute_iter(Alds + BM * BK, wr, wc, lane, B1, acch, accl);
        asm volatile("s_waitcnt vmcnt(0)" ::: "memory");
        __syncthreads();
    }

    // ---- accumulators -> LDS logits (C layout: col=lane&15, row=(lane>>4)*4+reg) ----
    #pragma unroll
    for (int rf = 0; rf < 2; ++rf) {
        #pragma unroll
        for (int cfi = 0; cfi < 2; ++cfi) {
            const int col  = wc * 32 + cfi * 16 + (lane & 15);
            const int rowb = wr * 32 + rf * 16 + (lane >> 4) * 4;
            #pragma unroll
            for (int r = 0; r < 4; ++r)
                Llds[rowb + r][col] = acch[rf][cfi][r] + accl[rf][cfi][r];
        }
    }
    __syncthreads();

    // ---- fused epilogue: 8 lanes per token, 8 experts each ----
    const int token = tid >> 3;          // 0..63
    const int s8    = tid & 7;
    const int tokG  = tokBase + token;

    double v0 = -INFINITY, v1 = -INFINITY;
    int i0 = 0, i1 = 0;
    const float* nz = noise + (size_t)tokG * E_EXP + s8 * 8;
    #pragma unroll
    for (int j = 0; j < 8; ++j) {
        const int e = s8 * 8 + j;
        const double lg = (double)Llds[token][e]      + (double)br[e];
        const double nl = (double)Llds[token][64 + e] + (double)bn[e];
        const double sp = fmax(nl, 0.0) + log1p(exp(-fabs(nl)));   // softplus
        const double v  = fma((double)nz[j], sp, lg);
        if (beats(v, e, v0, i0))      { v1 = v0; i1 = i0; v0 = v; i0 = e; }
        else if (beats(v, e, v1, i1)) { v1 = v;  i1 = e; }
    }
    // merge across the token's 8 lanes (aligned group, masks 1,2,4)
    #pragma unroll
    for (int m = 1; m < 8; m <<= 1) {
        const double w0 = __shfl_xor(v0, m), w1 = __shfl_xor(v1, m);
        const int    j0 = __shfl_xor(i0, m), j1 = __shfl_xor(i1, m);
        if (beats(v0, i0, w0, j0)) {
            if (!beats(v1, i1, w0, j0)) { v1 = w0; i1 = j0; }
        } else {
            if (beats(v0, i0, w1, j1)) { v1 = v0; i1 = i0; }
            else                       { v1 = w1; i1 = j1; }
            v0 = w0; i0 = j0;
        }
    }
    const double e1  = exp(v1 - v0);     // <= 1
    const double den = 1.0 + e1;
    const float p0 = (float)(1.0 / den);
    const float p1 = (float)(e1 / den);

    // every lane writes its own 8 cols -> no cross-thread write ordering needed
    float out[8];
    #pragma unroll
    for (int j = 0; j < 8; ++j) {
        const int e = s8 * 8 + j;
        out[j] = (e == i0) ? p0 : ((e == i1) ? p1 : 0.0f);
    }
    float* pb = probs + (size_t)tokG * E_EXP + s8 * 8;
    *(float4*)(pb)     = make_float4(out[0], out[1], out[2], out[3]);
    *(float4*)(pb + 4) = make_float4(out[4], out[5], out[6], out[7]);
    if (s8 == 0)
        *(float2*)(idxo + (size_t)tokG * 2) = make_float2((float)i0, (float)i1);
}

extern "C" void kernel_launch(void* const* d_in, const int* in_sizes, int n_in,
                              void* d_out, int out_size, void* d_ws, size_t ws_size,
                              hipStream_t stream) {
    (void)in_sizes; (void)n_in; (void)out_size; (void)ws_size;
    const float* A  = (const float*)d_in[0];   // mh_output [4,4096,2048]
    const float* Wr = (const float*)d_in[1];   // W_route   [2048,64]
    const float* br = (const float*)d_in[2];   // b_route   [64]
    const float* Wn = (const float*)d_in[3];   // W_noise   [2048,64]
    const float* bn = (const float*)d_in[4];   // b_noise   [64]
    const float* nz = (const float*)d_in[5];   // noise     [4,4096,64]

    float* probs = (float*)d_out;                    // [4,4096,64] f32
    float* idxo  = probs + (size_t)M_TOK * E_EXP;    // [4,4096,2] as float

    unsigned short* Wg = (unsigned short*)d_ws;      // 1.5 MB split-W, frag-linear

    prep_w<<<128, 256, 0, stream>>>(Wr, Wn, Wg);
    fused_router<<<M_TOK / BM, 512, 0, stream>>>(A, Wg, br, bn, nz, probs, idxo);
}

// Round 3
// 235.623 us; speedup vs baseline: 1.5703x; 1.1331x over previous
//
#include <hip/hip_runtime.h>
#include <math.h>

// Problem: B=4, S=4096, D=2048, E=64, TOP_K=2
#define M_TOK 16384
#define D_DIM 2048
#define E_EXP 64
#define NCOL  128              // route cols 0..63 | noise cols 64..127
#define BM    64               // tokens per block
#define BK    64               // K per main-loop iteration (2 MFMA substeps of 32)
#define NITER (D_DIM / BK)     // 32

// LDS: A limbs, frag-linear. Per row: 8 chunks x 16B (64 k bf16) + 16B skew.
// Row stride 144B = 36 words; 36 % 32 = 4 -> bank position = 4*((row+chunk)&7),
// balanced 8 lanes/position for full-wave b128 ops (conflict-minimal, no XOR).
#define ROW_STRIDE 144
#define PLANE (BM * ROW_STRIDE)        // 9216 B per limb plane
#define BUFSZ (3 * PLANE)              // 27648 B per K-tile buffer (3 limbs)
#define SMEM_BYTES (2 * BUFSZ)         // 55296 B (also aliased by epilogue Llds 33KB)

typedef float  f32x4  __attribute__((ext_vector_type(4)));
typedef short  bf16x8 __attribute__((ext_vector_type(8)));

#define MFMA_B16(a, b, c) __builtin_amdgcn_mfma_f32_16x16x32_bf16((a), (b), (c), 0, 0, 0)

// f32 -> bf16 round-to-nearest-even (identical limbs to the verified round-1 kernel)
__device__ __forceinline__ unsigned short bfrne(float f) {
    unsigned int u = __float_as_uint(f);
    return (unsigned short)((u + 0x7fffu + ((u >> 16) & 1u)) >> 16);
}
__device__ __forceinline__ float bfhi(unsigned short h) {
    return __uint_as_float((unsigned int)h << 16);
}

// jax.lax.top_k order: larger value first; ties -> lower index first
__device__ __forceinline__ bool beats(float va, int ia, float vb, int ib) {
    return (va > vb) || (va == vb && ia < ib);
}

// ---------------- prep: split W_route|W_noise into 3 bf16 limbs, frag-linear ----------
// Wg layout (16B units): [kblk 0..63][limb 0..2][cf 0..7][lane 0..63]
//   cf 0..3 -> route cols cf*16+(lane&15); cf 4..7 -> noise cols (cf-4)*16+(lane&15)
//   lane holds k = kblk*32 + (lane>>4)*8 + j  (exactly the mfma_16x16x32 B-frag order)
__global__ __launch_bounds__(256) void prep_w(
    const float* __restrict__ Wr, const float* __restrict__ Wn,
    unsigned short* __restrict__ Wg)
{
    const int g    = blockIdx.x * 256 + threadIdx.x;   // 0..32767
    const int lane = g & 63;
    const int cf   = (g >> 6) & 7;
    const int kblk = g >> 9;                           // 0..63
    const int colL = (cf & 3) * 16 + (lane & 15);
    const float* __restrict__ W = (cf < 4) ? Wr : Wn;
    const int kbase = kblk * 32 + (lane >> 4) * 8;

    bf16x8 o0, o1, o2;
    #pragma unroll
    for (int j = 0; j < 8; ++j) {
        const float w = W[(size_t)(kbase + j) * E_EXP + colL];
        const unsigned short h0 = bfrne(w);
        const float r  = w - bfhi(h0);              // exact
        const unsigned short h1 = bfrne(r);
        const float r2 = r - bfhi(h1);              // exact
        const unsigned short h2 = bfrne(r2);
        o0[j] = (short)h0; o1[j] = (short)h1; o2[j] = (short)h2;
    }
    const size_t s0 = (((size_t)kblk * 3 + 0) * 8 + cf) * 64 + lane;
    const size_t s1 = (((size_t)kblk * 3 + 1) * 8 + cf) * 64 + lane;
    const size_t s2 = (((size_t)kblk * 3 + 2) * 8 + cf) * 64 + lane;
    *(bf16x8*)(Wg + s0 * 8) = o0;
    *(bf16x8*)(Wg + s1 * 8) = o1;
    *(bf16x8*)(Wg + s2 * 8) = o2;
}

// ---------------- fused: 3-limb bf16 MFMA GEMM + softplus + top-2 + softmax ----------
__device__ __forceinline__ void load_b(const unsigned short* __restrict__ Wg,
                                       int it, int wc, int lane,
                                       bf16x8 (&Bv)[2][2][3])
{
    #pragma unroll
    for (int s = 0; s < 2; ++s) {
        const int kblk = it * 2 + s;
        #pragma unroll
        for (int cfi = 0; cfi < 2; ++cfi) {
            #pragma unroll
            for (int p = 0; p < 3; ++p) {
                const size_t idx = (((size_t)kblk * 3 + p) * 8 + (wc * 2 + cfi)) * 64 + lane;
                Bv[s][cfi][p] = *(const bf16x8*)(Wg + idx * 8);
            }
        }
    }
}

__device__ __forceinline__ void load_a(const float* __restrict__ A, int tokBase,
                                       int it, int tid, float4& x, float4& y)
{
    const int row = tid >> 3;          // 0..63
    const int kc8 = tid & 7;           // 8-float chunk within the 64-wide K tile
    const float* g = A + (size_t)(tokBase + row) * D_DIM + it * BK + kc8 * 8;
    x = *(const float4*)(g);
    y = *(const float4*)(g + 4);
}

__device__ __forceinline__ void split8(const float4& a, const float4& b,
                                       bf16x8& o0, bf16x8& o1, bf16x8& o2)
{
    const float v[8] = {a.x, a.y, a.z, a.w, b.x, b.y, b.z, b.w};
    #pragma unroll
    for (int j = 0; j < 8; ++j) {
        const unsigned short h0 = bfrne(v[j]);
        const float r  = v[j] - bfhi(h0);
        const unsigned short h1 = bfrne(r);
        const float r2 = r - bfhi(h1);
        const unsigned short h2 = bfrne(r2);
        o0[j] = (short)h0; o1[j] = (short)h1; o2[j] = (short)h2;
    }
}

// convert this thread's 8 A-floats into 3 bf16 limb chunks and store to LDS buffer
__device__ __forceinline__ void cvt_store(char* smem, int buf, int tid,
                                          const float4& x, const float4& y)
{
    bf16x8 h0, h1, h2;
    split8(x, y, h0, h1, h2);
    const int row = tid >> 3;
    const int kc8 = tid & 7;           // chunk index == s*4 + koct
    char* base = smem + buf * BUFSZ + row * ROW_STRIDE + kc8 * 16;
    *(bf16x8*)(base)             = h0;
    *(bf16x8*)(base + PLANE)     = h1;
    *(bf16x8*)(base + 2 * PLANE) = h2;
}

__device__ __forceinline__ void compute_iter(const char* Ab, int wr, int lane,
                                             const bf16x8 (&Bc)[2][2][3],
                                             f32x4 (&acch)[2][2], f32x4 (&accl)[2][2])
{
    #pragma unroll
    for (int s = 0; s < 2; ++s) {
        bf16x8 a0[2], a1[2], a2[2];
        #pragma unroll
        for (int rf = 0; rf < 2; ++rf) {
            const int row = wr * 32 + rf * 16 + (lane & 15);
            const int off = row * ROW_STRIDE + (s * 4 + (lane >> 4)) * 16;
            a0[rf] = *(const bf16x8*)(Ab + off);
            a1[rf] = *(const bf16x8*)(Ab + PLANE + off);
            a2[rf] = *(const bf16x8*)(Ab + 2 * PLANE + off);
        }
        #pragma unroll
        for (int cfi = 0; cfi < 2; ++cfi) {
            #pragma unroll
            for (int rf = 0; rf < 2; ++rf) {
                // hi limb product -> short dep chain in acch; 5 low products -> accl
                acch[rf][cfi] = MFMA_B16(a0[rf], Bc[s][cfi][0], acch[rf][cfi]);
                accl[rf][cfi] = MFMA_B16(a0[rf], Bc[s][cfi][1], accl[rf][cfi]);
                accl[rf][cfi] = MFMA_B16(a1[rf], Bc[s][cfi][0], accl[rf][cfi]);
                accl[rf][cfi] = MFMA_B16(a1[rf], Bc[s][cfi][1], accl[rf][cfi]);
                accl[rf][cfi] = MFMA_B16(a0[rf], Bc[s][cfi][2], accl[rf][cfi]);
                accl[rf][cfi] = MFMA_B16(a2[rf], Bc[s][cfi][0], accl[rf][cfi]);
            }
        }
    }
}

__global__ __launch_bounds__(512, 1) void fused_router(
    const float* __restrict__ A,
    const unsigned short* __restrict__ Wg,
    const float* __restrict__ br, const float* __restrict__ bn,
    const float* __restrict__ noise,
    float* __restrict__ probs, float* __restrict__ idxo)
{
    __shared__ __align__(16) char smem[SMEM_BYTES];   // A limbs (2 buf); epilogue aliases

    const int tid  = threadIdx.x;
    const int lane = tid & 63;
    const int wid  = tid >> 6;       // 0..7
    const int wr   = wid >> 2;       // token half  (32 tokens)
    const int wc   = wid & 3;        // col quarter (32 of 128 cols)
    const int tokBase = blockIdx.x * BM;

    f32x4 acch[2][2], accl[2][2];
    const f32x4 zero4 = {0.f, 0.f, 0.f, 0.f};
    #pragma unroll
    for (int a = 0; a < 2; ++a)
        #pragma unroll
        for (int b = 0; b < 2; ++b) { acch[a][b] = zero4; accl[a][b] = zero4; }

    bf16x8 B0[2][2][3], B1[2][2][3];
    float4 xE, yE, xO, yO;

    // prologue: limbs(0) -> buf0; A(1) in flight; B(0) in regs
    load_a(A, tokBase, 0, tid, xE, yE);
    load_b(Wg, 0, wc, lane, B0);
    load_a(A, tokBase, 1, tid, xO, yO);
    cvt_store(smem, 0, tid, xE, yE);          // compiler waits xE
    __syncthreads();

    #pragma unroll 1
    for (int it2 = 0; it2 < NITER / 2; ++it2) {
        const int ita = it2 * 2;
        const int itb = ita + 1;              // < NITER (NITER even)

        load_b(Wg, itb, wc, lane, B1);        // B for the odd sub-iter
        cvt_store(smem, 1, tid, xO, yO);      // limbs(itb) -> buf1 (buf1 idle since last barrier)
        if (ita + 2 < NITER) load_a(A, tokBase, ita + 2, tid, xE, yE);   // deep prefetch
        compute_iter(smem, wr, lane, B0, acch, accl);                    // consume buf0
        __syncthreads();                      // buf1 ready; buf0 reads done

        if (itb + 1 < NITER) load_b(Wg, itb + 1, wc, lane, B0);
        if (ita + 2 < NITER) cvt_store(smem, 0, tid, xE, yE);            // limbs(ita+2) -> buf0
        if (itb + 2 < NITER) load_a(A, tokBase, itb + 2, tid, xO, yO);
        compute_iter(smem + BUFSZ, wr, lane, B1, acch, accl);            // consume buf1
        __syncthreads();                      // buf0 ready; buf1 reads done
    }

    // ---- accumulators -> LDS logits (C layout: col=lane&15, row=(lane>>4)*4+reg) ----
    float (*Llds)[NCOL + 1] = (float (*)[NCOL + 1])smem;   // 64 x 129 f32, aliases A bufs
    #pragma unroll
    for (int rf = 0; rf < 2; ++rf) {
        #pragma unroll
        for (int cfi = 0; cfi < 2; ++cfi) {
            const int col  = wc * 32 + cfi * 16 + (lane & 15);
            const int rowb = wr * 32 + rf * 16 + (lane >> 4) * 4;
            #pragma unroll
            for (int r = 0; r < 4; ++r)
                Llds[rowb + r][col] = acch[rf][cfi][r] + accl[rf][cfi][r];
        }
    }
    __syncthreads();

    // ---- fused epilogue: 8 lanes per token, 8 experts each (f32; reference is f32) ----
    const int token = tid >> 3;          // 0..63
    const int s8    = tid & 7;
    const int tokG  = tokBase + token;

    float v0 = -INFINITY, v1 = -INFINITY;
    int i0 = 0, i1 = 0;
    const float* nz = noise + (size_t)tokG * E_EXP + s8 * 8;
    #pragma unroll
    for (int j = 0; j < 8; ++j) {
        const int e = s8 * 8 + j;
        const float lg = Llds[token][e]      + br[e];
        const float nl = Llds[token][64 + e] + bn[e];
        const float sp = fmaxf(nl, 0.0f) + log1pf(expf(-fabsf(nl)));   // softplus
        const float v  = fmaf(nz[j], sp, lg);
        if (beats(v, e, v0, i0))      { v1 = v0; i1 = i0; v0 = v; i0 = e; }
        else if (beats(v, e, v1, i1)) { v1 = v;  i1 = e; }
    }
    // merge across the token's 8 lanes (aligned group, masks 1,2,4)
    #pragma unroll
    for (int m = 1; m < 8; m <<= 1) {
        const float w0 = __shfl_xor(v0, m), w1 = __shfl_xor(v1, m);
        const int   j0 = __shfl_xor(i0, m), j1 = __shfl_xor(i1, m);
        if (beats(v0, i0, w0, j0)) {
            if (!beats(v1, i1, w0, j0)) { v1 = w0; i1 = j0; }
        } else {
            if (beats(v0, i0, w1, j1)) { v1 = v0; i1 = i0; }
            else                       { v1 = w1; i1 = j1; }
            v0 = w0; i0 = j0;
        }
    }
    const float e1  = expf(v1 - v0);     // <= 1
    const float den = 1.0f + e1;
    const float p0 = 1.0f / den;
    const float p1 = e1 / den;

    // every lane writes its own 8 cols -> no cross-thread write ordering needed
    float out[8];
    #pragma unroll
    for (int j = 0; j < 8; ++j) {
        const int e = s8 * 8 + j;
        out[j] = (e == i0) ? p0 : ((e == i1) ? p1 : 0.0f);
    }
    float* pb = probs + (size_t)tokG * E_EXP + s8 * 8;
    *(float4*)(pb)     = make_float4(out[0], out[1], out[2], out[3]);
    *(float4*)(pb + 4) = make_float4(out[4], out[5], out[6], out[7]);
    if (s8 == 0)
        *(float2*)(idxo + (size_t)tokG * 2) = make_float2((float)i0, (float)i1);
}

extern "C" void kernel_launch(void* const* d_in, const int* in_sizes, int n_in,
                              void* d_out, int out_size, void* d_ws, size_t ws_size,
                              hipStream_t stream) {
    (void)in_sizes; (void)n_in; (void)out_size; (void)ws_size;
    const float* A  = (const float*)d_in[0];   // mh_output [4,4096,2048]
    const float* Wr = (const float*)d_in[1];   // W_route   [2048,64]
    const float* br = (const float*)d_in[2];   // b_route   [64]
    const float* Wn = (const float*)d_in[3];   // W_noise   [2048,64]
    const float* bn = (const float*)d_in[4];   // b_noise   [64]
    const float* nz = (const float*)d_in[5];   // noise     [4,4096,64]

    float* probs = (float*)d_out;                    // [4,4096,64] f32
    float* idxo  = probs + (size_t)M_TOK * E_EXP;    // [4,4096,2] as float

    unsigned short* Wg = (unsigned short*)d_ws;      // 1.5 MB split-W, frag-linear

    prep_w<<<128, 256, 0, stream>>>(Wr, Wn, Wg);
    fused_router<<<M_TOK / BM, 512, 0, stream>>>(A, Wg, br, bn, nz, probs, idxo);
}